// Round 1
// baseline (4448.698 us; speedup 1.0000x reference)
//
#include <hip/hip_runtime.h>
#include <stdint.h>

// ---------------- Threefry2x32 (exact JAX semantics, 20 rounds) ----------------
__host__ __device__ static inline void tf2x32(uint32_t k0, uint32_t k1,
                                              uint32_t x0, uint32_t x1,
                                              uint32_t* o0, uint32_t* o1) {
  const uint32_t ks2 = k0 ^ k1 ^ 0x1BD11BDAu;
  x0 += k0; x1 += k1;
#define TF_RND(r) { x0 += x1; x1 = (x1 << (r)) | (x1 >> (32 - (r))); x1 ^= x0; }
  TF_RND(13) TF_RND(15) TF_RND(26) TF_RND(6)
  x0 += k1;  x1 += ks2 + 1u;
  TF_RND(17) TF_RND(29) TF_RND(16) TF_RND(24)
  x0 += ks2; x1 += k0 + 2u;
  TF_RND(13) TF_RND(15) TF_RND(26) TF_RND(6)
  x0 += k0;  x1 += k1 + 3u;
  TF_RND(17) TF_RND(29) TF_RND(16) TF_RND(24)
  x0 += k1;  x1 += ks2 + 4u;
  TF_RND(13) TF_RND(15) TF_RND(26) TF_RND(6)
  x0 += ks2; x1 += k0 + 5u;
#undef TF_RND
  *o0 = x0; *o1 = x1;
}

// jax_threefry_partitionable=True scheme: bits[i] = o0^o1 of tf(key, hi=0, lo=i)
__device__ static inline bool tf_keep(uint32_t k0, uint32_t k1, uint32_t idx) {
  uint32_t o0, o1;
  tf2x32(k0, k1, 0u, idx, &o0, &o1);
  const uint32_t bits = o0 ^ o1;
  const float u = __uint_as_float((bits >> 9) | 0x3f800000u) - 1.0f;
  return u < 0.9f;  // bernoulli(key, KEEP=0.9)
}

// ---------------- Edge scatter-add: agg[dst] += h[src] ----------------
// One thread per float4 chunk of one edge (32 threads/edge).
__global__ __launch_bounds__(256) void scatter_add_kernel(
    const float* __restrict__ h, const int* __restrict__ src,
    const int* __restrict__ dst, float* __restrict__ agg, int E) {
  const int tid = blockIdx.x * 256 + threadIdx.x;
  const int e = tid >> 5;
  if (e >= E) return;
  const int q = tid & 31;
  const int s = src[e];
  const int d = dst[e];
  const float4 v = ((const float4*)h)[(size_t)s * 32 + q];
  float* ap = agg + (size_t)d * 128 + (size_t)q * 4;
  atomicAdd(ap + 0, v.x);
  atomicAdd(ap + 1, v.y);
  atomicAdd(ap + 2, v.z);
  atomicAdd(ap + 3, v.w);
}

// ---------------- Fused GEMM (M x 128) @ (128 x NCOLS) + bias [+relu][+dropout] ----------------
// W staged in LDS (<=64KB). Block = 256 threads, BM=32 rows/block.
template <int NCOLS, bool RELU, bool DROPOUT>
__global__ __launch_bounds__(256) void mlp_gemm(
    const float* __restrict__ A, const float* __restrict__ W,
    const float* __restrict__ bias, float* __restrict__ out, int M,
    uint32_t k0, uint32_t k1) {
  constexpr int BM = 32;
  constexpr int COLT = NCOLS / 4;   // 32 (H=128) or 16 (O=64)
  constexpr int ROWT = 256 / COLT;  // 8 or 16
  constexpr int RPT = BM / ROWT;    // 4 or 2
  __shared__ float sW[128 * NCOLS];

  const int t = threadIdx.x;
  const int tc = t % COLT;
  const int tr = t / COLT;
  const int row0 = blockIdx.x * BM;

  for (int i = t; i < 128 * NCOLS / 4; i += 256)
    ((float4*)sW)[i] = ((const float4*)W)[i];
  __syncthreads();

  const float4* arow[RPT];
#pragma unroll
  for (int i = 0; i < RPT; ++i) {
    int r = row0 + tr + i * ROWT;
    if (r >= M) r = M - 1;  // clamp: results discarded at store
    arow[i] = (const float4*)(A + (size_t)r * 128);
  }

  float acc[RPT][4];
#pragma unroll
  for (int i = 0; i < RPT; ++i)
    acc[i][0] = acc[i][1] = acc[i][2] = acc[i][3] = 0.0f;

#pragma unroll 2
  for (int k4 = 0; k4 < 32; ++k4) {
    const float* wp = sW + k4 * 4 * NCOLS + tc * 4;
    const float4 w0 = *(const float4*)(wp);
    const float4 w1 = *(const float4*)(wp + NCOLS);
    const float4 w2 = *(const float4*)(wp + 2 * NCOLS);
    const float4 w3 = *(const float4*)(wp + 3 * NCOLS);
#pragma unroll
    for (int i = 0; i < RPT; ++i) {
      const float4 a = arow[i][k4];
      acc[i][0] = fmaf(a.w, w3.x, fmaf(a.z, w2.x, fmaf(a.y, w1.x, fmaf(a.x, w0.x, acc[i][0]))));
      acc[i][1] = fmaf(a.w, w3.y, fmaf(a.z, w2.y, fmaf(a.y, w1.y, fmaf(a.x, w0.y, acc[i][1]))));
      acc[i][2] = fmaf(a.w, w3.z, fmaf(a.z, w2.z, fmaf(a.y, w1.z, fmaf(a.x, w0.z, acc[i][2]))));
      acc[i][3] = fmaf(a.w, w3.w, fmaf(a.z, w2.w, fmaf(a.y, w1.w, fmaf(a.x, w0.w, acc[i][3]))));
    }
  }

  const float4 b = ((const float4*)bias)[tc];
  const float KEEP_INV = 1.0f / 0.9f;
#pragma unroll
  for (int i = 0; i < RPT; ++i) {
    const int r = row0 + tr + i * ROWT;
    if (r >= M) continue;
    float o0 = acc[i][0] + b.x, o1 = acc[i][1] + b.y;
    float o2 = acc[i][2] + b.z, o3 = acc[i][3] + b.w;
    if (RELU) {
      o0 = fmaxf(o0, 0.0f); o1 = fmaxf(o1, 0.0f);
      o2 = fmaxf(o2, 0.0f); o3 = fmaxf(o3, 0.0f);
    }
    if (DROPOUT) {  // only instantiated with NCOLS==128
      const uint32_t base = (uint32_t)r * 128u + (uint32_t)(tc * 4);
      o0 = tf_keep(k0, k1, base + 0u) ? o0 * KEEP_INV : 0.0f;
      o1 = tf_keep(k0, k1, base + 1u) ? o1 * KEEP_INV : 0.0f;
      o2 = tf_keep(k0, k1, base + 2u) ? o2 * KEEP_INV : 0.0f;
      o3 = tf_keep(k0, k1, base + 3u) ? o3 * KEEP_INV : 0.0f;
    }
    float4 ov; ov.x = o0; ov.y = o1; ov.z = o2; ov.w = o3;
    *(float4*)(out + (size_t)r * NCOLS + tc * 4) = ov;
  }
}

// ---------------- Host launch ----------------
extern "C" void kernel_launch(void* const* d_in, const int* in_sizes, int n_in,
                              void* d_out, int out_size, void* d_ws, size_t ws_size,
                              hipStream_t stream) {
  const float* x    = (const float*)d_in[0];
  const int*   ei   = (const int*)d_in[1];
  const float* Ws1  = (const float*)d_in[2];
  const float* bs1  = (const float*)d_in[3];
  const float* Ws2  = (const float*)d_in[4];
  const float* bs2  = (const float*)d_in[5];
  const float* Wlin = (const float*)d_in[6];
  const float* blin = (const float*)d_in[7];

  const int N = in_sizes[0] / 128;
  const int E = in_sizes[1] / 2;
  const int* src = ei;        // edge_index[0]
  const int* dst = ei + E;    // edge_index[1]

  float* bufA = (float*)d_ws;                   // N*128 floats
  float* bufB = bufA + (size_t)N * 128;         // N*128 floats

  // dkeys = partitionable (foldlike) split of key(42): dkey[l] = tf((0,42), 0, l)
  uint32_t dk[3][2];
  for (int l = 0; l < 3; ++l)
    tf2x32(0u, 42u, 0u, (uint32_t)l, &dk[l][0], &dk[l][1]);

  const int gemm_blocks = (N + 31) / 32;
  const int scat_blocks = (E * 32 + 255) / 256;

  const float* h = x;
  float* p = bufA;
  float* q = bufB;
  for (int l = 0; l < 3; ++l) {
    // p = h  (GIN eps=0 self term), then p += sum over incoming edges
    hipMemcpyAsync(p, h, (size_t)N * 128 * sizeof(float),
                   hipMemcpyDeviceToDevice, stream);
    scatter_add_kernel<<<scat_blocks, 256, 0, stream>>>(h, src, dst, p, E);
    // q = relu(p @ W1 + b1)
    mlp_gemm<128, true, false><<<gemm_blocks, 256, 0, stream>>>(
        p, Ws1 + (size_t)l * 128 * 128, bs1 + (size_t)l * 128, q, N, 0u, 0u);
    // p = dropout(relu(q @ W2 + b2))   (extra relu in ref is idempotent)
    mlp_gemm<128, true, true><<<gemm_blocks, 256, 0, stream>>>(
        q, Ws2 + (size_t)l * 128 * 128, bs2 + (size_t)l * 128, p, N,
        dk[l][0], dk[l][1]);
    h = p;
    float* tswap = p; p = q; q = tswap;
  }
  // out = h @ Wlin + blin
  mlp_gemm<64, false, false><<<gemm_blocks, 256, 0, stream>>>(
      h, Wlin, blin, (float*)d_out, N, 0u, 0u);
}

// Round 2
// 740.003 us; speedup vs baseline: 6.0117x; 6.0117x over previous
//
#include <hip/hip_runtime.h>
#include <stdint.h>

// ---------------- Threefry2x32 (exact JAX semantics, 20 rounds) ----------------
__host__ __device__ static inline void tf2x32(uint32_t k0, uint32_t k1,
                                              uint32_t x0, uint32_t x1,
                                              uint32_t* o0, uint32_t* o1) {
  const uint32_t ks2 = k0 ^ k1 ^ 0x1BD11BDAu;
  x0 += k0; x1 += k1;
#define TF_RND(r) { x0 += x1; x1 = (x1 << (r)) | (x1 >> (32 - (r))); x1 ^= x0; }
  TF_RND(13) TF_RND(15) TF_RND(26) TF_RND(6)
  x0 += k1;  x1 += ks2 + 1u;
  TF_RND(17) TF_RND(29) TF_RND(16) TF_RND(24)
  x0 += ks2; x1 += k0 + 2u;
  TF_RND(13) TF_RND(15) TF_RND(26) TF_RND(6)
  x0 += k0;  x1 += k1 + 3u;
  TF_RND(17) TF_RND(29) TF_RND(16) TF_RND(24)
  x0 += k1;  x1 += ks2 + 4u;
  TF_RND(13) TF_RND(15) TF_RND(26) TF_RND(6)
  x0 += ks2; x1 += k0 + 5u;
#undef TF_RND
  *o0 = x0; *o1 = x1;
}

__device__ static inline bool tf_keep(uint32_t k0, uint32_t k1, uint32_t idx) {
  uint32_t o0, o1;
  tf2x32(k0, k1, 0u, idx, &o0, &o1);
  const uint32_t bits = o0 ^ o1;
  const float u = __uint_as_float((bits >> 9) | 0x3f800000u) - 1.0f;
  return u < 0.9f;
}

// ---------------- CSR build: count / scan / fill ----------------
__global__ __launch_bounds__(256) void count_kernel(
    const int* __restrict__ dst, int* __restrict__ counts, int E) {
  const int e = blockIdx.x * 256 + threadIdx.x;
  if (e < E) atomicAdd(&counts[dst[e]], 1);
}

__global__ __launch_bounds__(1024) void scan_kernel(
    const int* __restrict__ counts, int* __restrict__ offsets, int N) {
  __shared__ int buf[1024];
  __shared__ int carry;
  const int t = threadIdx.x;
  if (t == 0) carry = 0;
  __syncthreads();
  for (int base = 0; base < N; base += 1024) {
    const int c = carry;
    const int i = base + t;
    buf[t] = (i < N) ? counts[i] : 0;
    __syncthreads();
    for (int off = 1; off < 1024; off <<= 1) {
      const int add = (t >= off) ? buf[t - off] : 0;
      __syncthreads();
      buf[t] += add;
      __syncthreads();
    }
    if (i < N) offsets[i + 1] = c + buf[t];
    if (i == 0) offsets[0] = 0;
    const int total = buf[1023];
    __syncthreads();
    if (t == 0) carry = c + total;
    __syncthreads();
  }
}

__global__ __launch_bounds__(256) void fill_kernel(
    const int* __restrict__ src, const int* __restrict__ dst,
    int* __restrict__ cursor, int* __restrict__ csr, int E) {
  const int e = blockIdx.x * 256 + threadIdx.x;
  if (e < E) {
    const int pos = atomicAdd(&cursor[dst[e]], 1);
    csr[pos] = src[e];
  }
}

// ---------------- Gather-sum: out[i] = h[i] + sum_{e in CSR(i)} h[csr[e]] ----------------
// 32 threads per node, one float4 per thread.
__global__ __launch_bounds__(256) void gather_kernel(
    const float* __restrict__ h, const int* __restrict__ csr,
    const int* __restrict__ off, float* __restrict__ out, int N) {
  const int tid = blockIdx.x * 256 + threadIdx.x;
  const int node = tid >> 5;
  if (node >= N) return;
  const int q = tid & 31;
  const int beg = off[node];
  const int end = off[node + 1];
  const float4* hv = (const float4*)h;
  float4 acc = hv[(size_t)node * 32 + q];  // self term (eps=0)
  int e = beg;
  for (; e + 2 <= end; e += 2) {
    const int s0 = csr[e];
    const int s1 = csr[e + 1];
    const float4 v0 = hv[(size_t)s0 * 32 + q];
    const float4 v1 = hv[(size_t)s1 * 32 + q];
    acc.x += v0.x + v1.x; acc.y += v0.y + v1.y;
    acc.z += v0.z + v1.z; acc.w += v0.w + v1.w;
  }
  if (e < end) {
    const float4 v = hv[(size_t)csr[e] * 32 + q];
    acc.x += v.x; acc.y += v.y; acc.z += v.z; acc.w += v.w;
  }
  ((float4*)out)[(size_t)node * 32 + q] = acc;
}

// ---------------- Fused GEMM (M x 128) @ (128 x NCOLS) + bias [+relu][+dropout] ----------------
template <int NCOLS, bool RELU, bool DROPOUT>
__global__ __launch_bounds__(256) void mlp_gemm(
    const float* __restrict__ A, const float* __restrict__ W,
    const float* __restrict__ bias, float* __restrict__ out, int M,
    uint32_t k0, uint32_t k1) {
  constexpr int BM = 32;
  constexpr int COLT = NCOLS / 4;
  constexpr int ROWT = 256 / COLT;
  constexpr int RPT = BM / ROWT;
  __shared__ float sW[128 * NCOLS];

  const int t = threadIdx.x;
  const int tc = t % COLT;
  const int tr = t / COLT;
  const int row0 = blockIdx.x * BM;

  for (int i = t; i < 128 * NCOLS / 4; i += 256)
    ((float4*)sW)[i] = ((const float4*)W)[i];
  __syncthreads();

  const float4* arow[RPT];
#pragma unroll
  for (int i = 0; i < RPT; ++i) {
    int r = row0 + tr + i * ROWT;
    if (r >= M) r = M - 1;
    arow[i] = (const float4*)(A + (size_t)r * 128);
  }

  float acc[RPT][4];
#pragma unroll
  for (int i = 0; i < RPT; ++i)
    acc[i][0] = acc[i][1] = acc[i][2] = acc[i][3] = 0.0f;

#pragma unroll 2
  for (int k4 = 0; k4 < 32; ++k4) {
    const float* wp = sW + k4 * 4 * NCOLS + tc * 4;
    const float4 w0 = *(const float4*)(wp);
    const float4 w1 = *(const float4*)(wp + NCOLS);
    const float4 w2 = *(const float4*)(wp + 2 * NCOLS);
    const float4 w3 = *(const float4*)(wp + 3 * NCOLS);
#pragma unroll
    for (int i = 0; i < RPT; ++i) {
      const float4 a = arow[i][k4];
      acc[i][0] = fmaf(a.w, w3.x, fmaf(a.z, w2.x, fmaf(a.y, w1.x, fmaf(a.x, w0.x, acc[i][0]))));
      acc[i][1] = fmaf(a.w, w3.y, fmaf(a.z, w2.y, fmaf(a.y, w1.y, fmaf(a.x, w0.y, acc[i][1]))));
      acc[i][2] = fmaf(a.w, w3.z, fmaf(a.z, w2.z, fmaf(a.y, w1.z, fmaf(a.x, w0.z, acc[i][2]))));
      acc[i][3] = fmaf(a.w, w3.w, fmaf(a.z, w2.w, fmaf(a.y, w1.w, fmaf(a.x, w0.w, acc[i][3]))));
    }
  }

  const float4 b = ((const float4*)bias)[tc];
  const float KEEP_INV = 1.0f / 0.9f;
#pragma unroll
  for (int i = 0; i < RPT; ++i) {
    const int r = row0 + tr + i * ROWT;
    if (r >= M) continue;
    float o0 = acc[i][0] + b.x, o1 = acc[i][1] + b.y;
    float o2 = acc[i][2] + b.z, o3 = acc[i][3] + b.w;
    if (RELU) {
      o0 = fmaxf(o0, 0.0f); o1 = fmaxf(o1, 0.0f);
      o2 = fmaxf(o2, 0.0f); o3 = fmaxf(o3, 0.0f);
    }
    if (DROPOUT) {
      const uint32_t base = (uint32_t)r * 128u + (uint32_t)(tc * 4);
      o0 = tf_keep(k0, k1, base + 0u) ? o0 * KEEP_INV : 0.0f;
      o1 = tf_keep(k0, k1, base + 1u) ? o1 * KEEP_INV : 0.0f;
      o2 = tf_keep(k0, k1, base + 2u) ? o2 * KEEP_INV : 0.0f;
      o3 = tf_keep(k0, k1, base + 3u) ? o3 * KEEP_INV : 0.0f;
    }
    float4 ov; ov.x = o0; ov.y = o1; ov.z = o2; ov.w = o3;
    *(float4*)(out + (size_t)r * NCOLS + tc * 4) = ov;
  }
}

// ---------------- Host launch ----------------
extern "C" void kernel_launch(void* const* d_in, const int* in_sizes, int n_in,
                              void* d_out, int out_size, void* d_ws, size_t ws_size,
                              hipStream_t stream) {
  const float* x    = (const float*)d_in[0];
  const int*   ei   = (const int*)d_in[1];
  const float* Ws1  = (const float*)d_in[2];
  const float* bs1  = (const float*)d_in[3];
  const float* Ws2  = (const float*)d_in[4];
  const float* bs2  = (const float*)d_in[5];
  const float* Wlin = (const float*)d_in[6];
  const float* blin = (const float*)d_in[7];

  const int N = in_sizes[0] / 128;
  const int E = in_sizes[1] / 2;
  const int* src = ei;
  const int* dst = ei + E;

  // Workspace layout: 2 ping-pong feature buffers + CSR arrays (~55 MB)
  float* bufA   = (float*)d_ws;                  // N*128 f32
  float* bufB   = bufA + (size_t)N * 128;        // N*128 f32
  int* counts   = (int*)(bufB + (size_t)N * 128);// N
  int* offsets  = counts + N;                    // N+1
  int* cursor   = offsets + N + 1;               // N
  int* csr      = cursor + N;                    // E

  // dkeys: partitionable split of key(42): dkey[l] = tf((0,42), 0, l)
  uint32_t dk[3][2];
  for (int l = 0; l < 3; ++l)
    tf2x32(0u, 42u, 0u, (uint32_t)l, &dk[l][0], &dk[l][1]);

  const int eblocks = (E + 255) / 256;
  const int nblocks32 = (N * 32 + 255) / 256;
  const int gemm_blocks = (N + 31) / 32;

  // ---- CSR build (once per call; graph is layer-invariant) ----
  hipMemsetAsync(counts, 0, (size_t)N * sizeof(int), stream);
  count_kernel<<<eblocks, 256, 0, stream>>>(dst, counts, E);
  scan_kernel<<<1, 1024, 0, stream>>>(counts, offsets, N);
  hipMemcpyAsync(cursor, offsets, (size_t)N * sizeof(int),
                 hipMemcpyDeviceToDevice, stream);
  fill_kernel<<<eblocks, 256, 0, stream>>>(src, dst, cursor, csr, E);

  // ---- 3 GIN layers ----
  const float* h = x;
  float* p = bufA;
  float* q = bufB;
  for (int l = 0; l < 3; ++l) {
    gather_kernel<<<nblocks32, 256, 0, stream>>>(h, csr, offsets, p, N);
    mlp_gemm<128, true, false><<<gemm_blocks, 256, 0, stream>>>(
        p, Ws1 + (size_t)l * 128 * 128, bs1 + (size_t)l * 128, q, N, 0u, 0u);
    mlp_gemm<128, true, true><<<gemm_blocks, 256, 0, stream>>>(
        q, Ws2 + (size_t)l * 128 * 128, bs2 + (size_t)l * 128, p, N,
        dk[l][0], dk[l][1]);
    h = p;
    float* tswap = p; p = q; q = tswap;
  }
  mlp_gemm<64, false, false><<<gemm_blocks, 256, 0, stream>>>(
      h, Wlin, blin, (float*)d_out, N, 0u, 0u);
}

// Round 3
// 494.222 us; speedup vs baseline: 9.0014x; 1.4973x over previous
//
#include <hip/hip_runtime.h>
#include <stdint.h>

typedef short short8 __attribute__((ext_vector_type(8)));   // 8 bf16 raw (4 VGPRs)
typedef float float4v __attribute__((ext_vector_type(4)));  // MFMA C/D frag

// ---------------- bf16 helpers (RNE) ----------------
__device__ static inline unsigned short f2bf(float f) {
  uint32_t u = __float_as_uint(f);
  u += 0x7fffu + ((u >> 16) & 1u);
  return (unsigned short)(u >> 16);
}
__device__ static inline float bf_lo(uint32_t v) { return __uint_as_float(v << 16); }
__device__ static inline float bf_hi(uint32_t v) { return __uint_as_float(v & 0xffff0000u); }

// ---------------- Threefry2x32 (exact JAX semantics, 20 rounds) ----------------
__host__ __device__ static inline void tf2x32(uint32_t k0, uint32_t k1,
                                              uint32_t x0, uint32_t x1,
                                              uint32_t* o0, uint32_t* o1) {
  const uint32_t ks2 = k0 ^ k1 ^ 0x1BD11BDAu;
  x0 += k0; x1 += k1;
#define TF_RND(r) { x0 += x1; x1 = (x1 << (r)) | (x1 >> (32 - (r))); x1 ^= x0; }
  TF_RND(13) TF_RND(15) TF_RND(26) TF_RND(6)
  x0 += k1;  x1 += ks2 + 1u;
  TF_RND(17) TF_RND(29) TF_RND(16) TF_RND(24)
  x0 += ks2; x1 += k0 + 2u;
  TF_RND(13) TF_RND(15) TF_RND(26) TF_RND(6)
  x0 += k0;  x1 += k1 + 3u;
  TF_RND(17) TF_RND(29) TF_RND(16) TF_RND(24)
  x0 += k1;  x1 += ks2 + 4u;
  TF_RND(13) TF_RND(15) TF_RND(26) TF_RND(6)
  x0 += ks2; x1 += k0 + 5u;
#undef TF_RND
  *o0 = x0; *o1 = x1;
}

__device__ static inline bool tf_keep(uint32_t k0, uint32_t k1, uint32_t idx) {
  uint32_t o0, o1;
  tf2x32(k0, k1, 0u, idx, &o0, &o1);
  const uint32_t bits = o0 ^ o1;
  const float u = __uint_as_float((bits >> 9) | 0x3f800000u) - 1.0f;
  return u < 0.9f;
}

// ---------------- CSR build ----------------
__global__ __launch_bounds__(256) void count_kernel(
    const int* __restrict__ dst, int* __restrict__ counts, int E) {
  const int e = blockIdx.x * 256 + threadIdx.x;
  if (e < E) atomicAdd(&counts[dst[e]], 1);
}

// Single block, 1024 threads: serial chunk sums -> 1024-wide scan -> serial writeback.
__global__ __launch_bounds__(1024) void scan_kernel(
    const int* __restrict__ counts, int* __restrict__ offsets, int N) {
  __shared__ int partial[1024];
  const int t = threadIdx.x;
  const int C = (N + 1023) / 1024;
  const int base = t * C;
  int s = 0;
  for (int i = 0; i < C; ++i) {
    const int idx = base + i;
    if (idx < N) s += counts[idx];
  }
  partial[t] = s;
  __syncthreads();
  for (int off = 1; off < 1024; off <<= 1) {
    const int add = (t >= off) ? partial[t - off] : 0;
    __syncthreads();
    partial[t] += add;
    __syncthreads();
  }
  int run = (t == 0) ? 0 : partial[t - 1];
  if (t == 0) offsets[0] = 0;
  for (int i = 0; i < C; ++i) {
    const int idx = base + i;
    if (idx < N) { run += counts[idx]; offsets[idx + 1] = run; }
  }
}

__global__ __launch_bounds__(256) void fill_kernel(
    const int* __restrict__ src, const int* __restrict__ dst,
    int* __restrict__ cursor, int* __restrict__ csr, int E) {
  const int e = blockIdx.x * 256 + threadIdx.x;
  if (e < E) {
    const int pos = atomicAdd(&cursor[dst[e]], 1);
    csr[pos] = src[e];
  }
}

// ---------------- x (fp32) -> bf16 ----------------
__global__ __launch_bounds__(256) void convert_kernel(
    const float* __restrict__ x, unsigned short* __restrict__ xb, int n4) {
  const int i = blockIdx.x * 256 + threadIdx.x;
  if (i >= n4) return;
  const float4 v = ((const float4*)x)[i];
  uint2 o;
  o.x = (uint32_t)f2bf(v.x) | ((uint32_t)f2bf(v.y) << 16);
  o.y = (uint32_t)f2bf(v.z) | ((uint32_t)f2bf(v.w) << 16);
  ((uint2*)xb)[i] = o;
}

// ---------------- Repack fp32 W -> bf16 MFMA B-fragment layout ----------------
// Layout per matrix: [ch][kt(4)][nt(4)][lane(64)][j(8)]; B[k][n], k=kt*32+(lane>>4)*8+j,
// n=ch*64+nt*16+(lane&15). Six 128x128 (W1[0],W2[0],W1[1],W2[1],W1[2],W2[2]) then Wlin 128x64.
__global__ __launch_bounds__(256) void repack_kernel(
    const float* __restrict__ Ws1, const float* __restrict__ Ws2,
    const float* __restrict__ Wlin, unsigned short* __restrict__ wpack) {
  const int tid = blockIdx.x * 256 + threadIdx.x;  // 13312 total
  const float* W;
  int cols, r;
  size_t obase;
  if (tid < 12288) {
    const int m = tid / 2048;  // 0..5
    r = tid % 2048;
    const int l = m >> 1;
    W = (m & 1) ? (Ws2 + (size_t)l * 16384) : (Ws1 + (size_t)l * 16384);
    cols = 128;
    obase = (size_t)m * 16384;
  } else {
    r = tid - 12288;           // 0..1023
    W = Wlin;
    cols = 64;
    obase = 6 * 16384;
  }
  const int ch = (cols == 128) ? (r >> 10) : 0;
  const int kt = (r >> 8) & 3;
  const int nt = (r >> 6) & 3;
  const int lane = r & 63;
  const int n = ch * 64 + nt * 16 + (lane & 15);
  const int kbase = kt * 32 + (lane >> 4) * 8;
  unsigned short o[8];
#pragma unroll
  for (int j = 0; j < 8; ++j) o[j] = f2bf(W[(size_t)(kbase + j) * cols + n]);
  uint4 ov;
  ov.x = (uint32_t)o[0] | ((uint32_t)o[1] << 16);
  ov.y = (uint32_t)o[2] | ((uint32_t)o[3] << 16);
  ov.z = (uint32_t)o[4] | ((uint32_t)o[5] << 16);
  ov.w = (uint32_t)o[6] | ((uint32_t)o[7] << 16);
  *(uint4*)(wpack + obase + ((size_t)((ch * 16 + kt * 4 + nt) * 64 + lane)) * 8) = ov;
}

// ---------------- Gather-sum (bf16 in/out, fp32 accumulate) ----------------
// 32 threads per node; 4 bf16 (8B) per thread.
__global__ __launch_bounds__(256) void gather_kernel(
    const unsigned short* __restrict__ h, const int* __restrict__ csr,
    const int* __restrict__ off, unsigned short* __restrict__ out, int N) {
  const int tid = blockIdx.x * 256 + threadIdx.x;
  const int node = tid >> 5;
  if (node >= N) return;
  const int q = tid & 31;
  const uint2* hv = (const uint2*)h;
  const int beg = off[node];
  const int end = off[node + 1];
  uint2 sv = hv[(size_t)node * 32 + q];
  float a0 = bf_lo(sv.x), a1 = bf_hi(sv.x), a2 = bf_lo(sv.y), a3 = bf_hi(sv.y);
  int e = beg;
  for (; e + 2 <= end; e += 2) {
    const uint2 v0 = hv[(size_t)csr[e] * 32 + q];
    const uint2 v1 = hv[(size_t)csr[e + 1] * 32 + q];
    a0 += bf_lo(v0.x) + bf_lo(v1.x);
    a1 += bf_hi(v0.x) + bf_hi(v1.x);
    a2 += bf_lo(v0.y) + bf_lo(v1.y);
    a3 += bf_hi(v0.y) + bf_hi(v1.y);
  }
  if (e < end) {
    const uint2 v = hv[(size_t)csr[e] * 32 + q];
    a0 += bf_lo(v.x); a1 += bf_hi(v.x); a2 += bf_lo(v.y); a3 += bf_hi(v.y);
  }
  uint2 o;
  o.x = (uint32_t)f2bf(a0) | ((uint32_t)f2bf(a1) << 16);
  o.y = (uint32_t)f2bf(a2) | ((uint32_t)f2bf(a3) << 16);
  ((uint2*)out)[(size_t)node * 32 + q] = o;
}

// ---------------- MFMA GEMM: (M x 128 bf16) @ (128 x COLS) + bias [+relu][+drop] ----------------
// Block = 4 waves. COLS=128: wave -> (row-tile rt = w/2, col-half ch = w&1), 32 rows/block.
// COLS=64: wave -> rt = w, ch = 0, 64 rows/block. B held in registers (16 frags).
template <int COLS, bool RELU, bool DROPOUT, bool OUT_BF16>
__global__ __launch_bounds__(256) void mfma_gemm(
    const unsigned short* __restrict__ A, const unsigned short* __restrict__ Wp,
    const float* __restrict__ bias, void* __restrict__ outv, int M,
    uint32_t k0, uint32_t k1) {
  constexpr int CH = COLS / 64;      // 2 or 1
  constexpr int BROWS = (4 / CH) * 16;
  const int wave = threadIdx.x >> 6;
  const int lane = threadIdx.x & 63;
  const int ch = wave % CH;
  const int rt = wave / CH;
  const int m = lane & 15;
  const int kg = lane >> 4;

  // B fragments: 16 x short8
  short8 bfrag[16];
  const short8* wp = (const short8*)Wp + (size_t)(ch * 16) * 64 + lane;
#pragma unroll
  for (int i = 0; i < 16; ++i) bfrag[i] = wp[(size_t)i * 64];

  const int row0 = blockIdx.x * BROWS + rt * 16;
  const int arow = (row0 + m < M) ? (row0 + m) : (M - 1);
  const short8* ap = (const short8*)(A + (size_t)arow * 128 + kg * 8);

  short8 afrag[4];
#pragma unroll
  for (int kt = 0; kt < 4; ++kt) afrag[kt] = ap[kt * 4];

  float4v acc[4] = {};
#pragma unroll
  for (int kt = 0; kt < 4; ++kt) {
#pragma unroll
    for (int nt = 0; nt < 4; ++nt)
      acc[nt] = __builtin_amdgcn_mfma_f32_16x16x32_bf16(
          afrag[kt], bfrag[kt * 4 + nt], acc[nt], 0, 0, 0);
  }

  // Epilogue: C/D layout col=lane&15, row=kg*4+reg
  const float KEEP_INV = 1.0f / 0.9f;
#pragma unroll
  for (int nt = 0; nt < 4; ++nt) {
    const int col = ch * 64 + nt * 16 + m;
    const float b = bias[col];
#pragma unroll
    for (int r = 0; r < 4; ++r) {
      const int ro = row0 + kg * 4 + r;
      if (ro >= M) continue;
      float v = acc[nt][r] + b;
      if (RELU) v = fmaxf(v, 0.0f);
      if (DROPOUT) {
        const uint32_t idx = (uint32_t)ro * 128u + (uint32_t)col;
        v = tf_keep(k0, k1, idx) ? v * KEEP_INV : 0.0f;
      }
      if (OUT_BF16)
        ((unsigned short*)outv)[(size_t)ro * COLS + col] = f2bf(v);
      else
        ((float*)outv)[(size_t)ro * COLS + col] = v;
    }
  }
}

// ---------------- Host launch ----------------
extern "C" void kernel_launch(void* const* d_in, const int* in_sizes, int n_in,
                              void* d_out, int out_size, void* d_ws, size_t ws_size,
                              hipStream_t stream) {
  const float* x    = (const float*)d_in[0];
  const int*   ei   = (const int*)d_in[1];
  const float* Ws1  = (const float*)d_in[2];
  const float* bs1  = (const float*)d_in[3];
  const float* Ws2  = (const float*)d_in[4];
  const float* bs2  = (const float*)d_in[5];
  const float* Wlin = (const float*)d_in[6];
  const float* blin = (const float*)d_in[7];

  const int N = in_sizes[0] / 128;
  const int E = in_sizes[1] / 2;
  const int* src = ei;
  const int* dst = ei + E;

  // Workspace: 3 bf16 feature buffers + CSR + repacked weights (~43 MB)
  unsigned short* bufA = (unsigned short*)d_ws;           // h      (N*128 bf16)
  unsigned short* bufB = bufA + (size_t)N * 128;          // agg
  unsigned short* bufC = bufB + (size_t)N * 128;          // t1
  unsigned short* wpack = bufC + (size_t)N * 128;         // 106496 bf16
  int* counts  = (int*)(wpack + 106496 + 16);
  int* offsets = counts + N;
  int* cursor  = offsets + N + 1;
  int* csr     = cursor + N;

  uint32_t dk[3][2];
  for (int l = 0; l < 3; ++l)
    tf2x32(0u, 42u, 0u, (uint32_t)l, &dk[l][0], &dk[l][1]);

  const int eblocks = (E + 255) / 256;
  const int nblocks32 = (N * 32 + 255) / 256;

  // CSR build
  hipMemsetAsync(counts, 0, (size_t)N * sizeof(int), stream);
  count_kernel<<<eblocks, 256, 0, stream>>>(dst, counts, E);
  scan_kernel<<<1, 1024, 0, stream>>>(counts, offsets, N);
  hipMemcpyAsync(cursor, offsets, (size_t)N * sizeof(int),
                 hipMemcpyDeviceToDevice, stream);
  fill_kernel<<<eblocks, 256, 0, stream>>>(src, dst, cursor, csr, E);

  // Prep: x->bf16, weights->MFMA fragment layout
  convert_kernel<<<(N * 32 + 255) / 256, 256, 0, stream>>>(x, bufA, N * 32);
  repack_kernel<<<52, 256, 0, stream>>>(Ws1, Ws2, Wlin, wpack);

  const int g128 = (N + 31) / 32;
  const int g64  = (N + 63) / 64;

  for (int l = 0; l < 3; ++l) {
    gather_kernel<<<nblocks32, 256, 0, stream>>>(bufA, csr, offsets, bufB, N);
    mfma_gemm<128, true, false, true><<<g128, 256, 0, stream>>>(
        bufB, wpack + (size_t)(l * 2) * 16384, bs1 + (size_t)l * 128, bufC, N, 0u, 0u);
    mfma_gemm<128, true, true, true><<<g128, 256, 0, stream>>>(
        bufC, wpack + (size_t)(l * 2 + 1) * 16384, bs2 + (size_t)l * 128, bufA, N,
        dk[l][0], dk[l][1]);
  }
  mfma_gemm<64, false, false, false><<<g64, 256, 0, stream>>>(
      bufA, wpack + 6 * 16384, blin, d_out, N, 0u, 0u);
}

// Round 4
// 385.032 us; speedup vs baseline: 11.5541x; 1.2836x over previous
//
#include <hip/hip_runtime.h>
#include <stdint.h>

typedef short short8 __attribute__((ext_vector_type(8)));   // 8 bf16 raw (4 VGPRs)
typedef float float4v __attribute__((ext_vector_type(4)));  // MFMA C/D frag

// ---------------- bf16 helpers (RNE) ----------------
__device__ static inline unsigned short f2bf(float f) {
  uint32_t u = __float_as_uint(f);
  u += 0x7fffu + ((u >> 16) & 1u);
  return (unsigned short)(u >> 16);
}
__device__ static inline float bf_lo(uint32_t v) { return __uint_as_float(v << 16); }
__device__ static inline float bf_hi(uint32_t v) { return __uint_as_float(v & 0xffff0000u); }

// ---------------- Threefry2x32 (exact JAX semantics, 20 rounds) ----------------
__host__ __device__ static inline void tf2x32(uint32_t k0, uint32_t k1,
                                              uint32_t x0, uint32_t x1,
                                              uint32_t* o0, uint32_t* o1) {
  const uint32_t ks2 = k0 ^ k1 ^ 0x1BD11BDAu;
  x0 += k0; x1 += k1;
#define TF_RND(r) { x0 += x1; x1 = (x1 << (r)) | (x1 >> (32 - (r))); x1 ^= x0; }
  TF_RND(13) TF_RND(15) TF_RND(26) TF_RND(6)
  x0 += k1;  x1 += ks2 + 1u;
  TF_RND(17) TF_RND(29) TF_RND(16) TF_RND(24)
  x0 += ks2; x1 += k0 + 2u;
  TF_RND(13) TF_RND(15) TF_RND(26) TF_RND(6)
  x0 += k0;  x1 += k1 + 3u;
  TF_RND(17) TF_RND(29) TF_RND(16) TF_RND(24)
  x0 += k1;  x1 += ks2 + 4u;
  TF_RND(13) TF_RND(15) TF_RND(26) TF_RND(6)
  x0 += ks2; x1 += k0 + 5u;
#undef TF_RND
  *o0 = x0; *o1 = x1;
}

__device__ static inline bool tf_keep(uint32_t k0, uint32_t k1, uint32_t idx) {
  uint32_t o0, o1;
  tf2x32(k0, k1, 0u, idx, &o0, &o1);
  const uint32_t bits = o0 ^ o1;
  const float u = __uint_as_float((bits >> 9) | 0x3f800000u) - 1.0f;
  return u < 0.9f;
}

// ---------------- CSR build ----------------
__global__ __launch_bounds__(256) void count_kernel(
    const int* __restrict__ dst, int* __restrict__ counts, int E) {
  const int e = blockIdx.x * 256 + threadIdx.x;
  if (e < E) atomicAdd(&counts[dst[e]], 1);
}

// Phase 1: per-block (256-elem) sums
__global__ __launch_bounds__(256) void scan1_kernel(
    const int* __restrict__ counts, int* __restrict__ bsum, int N) {
  __shared__ int red[4];
  const int i = blockIdx.x * 256 + threadIdx.x;
  int v = (i < N) ? counts[i] : 0;
  for (int off = 32; off > 0; off >>= 1) v += __shfl_down(v, off, 64);
  if ((threadIdx.x & 63) == 0) red[threadIdx.x >> 6] = v;
  __syncthreads();
  if (threadIdx.x == 0) bsum[blockIdx.x] = red[0] + red[1] + red[2] + red[3];
}

// Phase 2: exclusive scan of block sums (nb <= 256), in place
__global__ __launch_bounds__(256) void scan2_kernel(int* __restrict__ bsum, int nb) {
  __shared__ int buf[256];
  const int t = threadIdx.x;
  buf[t] = (t < nb) ? bsum[t] : 0;
  __syncthreads();
  for (int off = 1; off < 256; off <<= 1) {
    const int add = (t >= off) ? buf[t - off] : 0;
    __syncthreads();
    buf[t] += add;
    __syncthreads();
  }
  if (t < nb) bsum[t] = (t == 0) ? 0 : buf[t - 1];
}

// Phase 3: block-local inclusive scan + bsum -> offsets[i+1], cursor[i]=offsets[i]
__global__ __launch_bounds__(256) void scan3_kernel(
    const int* __restrict__ counts, const int* __restrict__ bsum,
    int* __restrict__ offsets, int* __restrict__ cursor, int N) {
  __shared__ int buf[256];
  const int t = threadIdx.x;
  const int i = blockIdx.x * 256 + t;
  const int c = (i < N) ? counts[i] : 0;
  buf[t] = c;
  __syncthreads();
  for (int off = 1; off < 256; off <<= 1) {
    const int add = (t >= off) ? buf[t - off] : 0;
    __syncthreads();
    buf[t] += add;
    __syncthreads();
  }
  if (i < N) {
    const int incl = bsum[blockIdx.x] + buf[t];
    offsets[i + 1] = incl;
    cursor[i] = incl - c;
    if (i == 0) offsets[0] = 0;
  }
}

__global__ __launch_bounds__(256) void fill_kernel(
    const int* __restrict__ src, const int* __restrict__ dst,
    int* __restrict__ cursor, int* __restrict__ csr, int E) {
  const int e = blockIdx.x * 256 + threadIdx.x;
  if (e < E) {
    const int pos = atomicAdd(&cursor[dst[e]], 1);
    csr[pos] = src[e];
  }
}

// ---------------- x (fp32) -> bf16 ----------------
__global__ __launch_bounds__(256) void convert_kernel(
    const float* __restrict__ x, unsigned short* __restrict__ xb, int n4) {
  const int i = blockIdx.x * 256 + threadIdx.x;
  if (i >= n4) return;
  const float4 v = ((const float4*)x)[i];
  uint2 o;
  o.x = (uint32_t)f2bf(v.x) | ((uint32_t)f2bf(v.y) << 16);
  o.y = (uint32_t)f2bf(v.z) | ((uint32_t)f2bf(v.w) << 16);
  ((uint2*)xb)[i] = o;
}

// ---------------- Repack fp32 W -> bf16 MFMA B-fragment layout ----------------
__global__ __launch_bounds__(256) void repack_kernel(
    const float* __restrict__ Ws1, const float* __restrict__ Ws2,
    const float* __restrict__ Wlin, unsigned short* __restrict__ wpack) {
  const int tid = blockIdx.x * 256 + threadIdx.x;  // 13312 total
  const float* W;
  int cols, r;
  size_t obase;
  if (tid < 12288) {
    const int m = tid / 2048;  // 0..5
    r = tid % 2048;
    const int l = m >> 1;
    W = (m & 1) ? (Ws2 + (size_t)l * 16384) : (Ws1 + (size_t)l * 16384);
    cols = 128;
    obase = (size_t)m * 16384;
  } else {
    r = tid - 12288;           // 0..1023
    W = Wlin;
    cols = 64;
    obase = 6 * 16384;
  }
  const int ch = (cols == 128) ? (r >> 10) : 0;
  const int kt = (r >> 8) & 3;
  const int nt = (r >> 6) & 3;
  const int lane = r & 63;
  const int n = ch * 64 + nt * 16 + (lane & 15);
  const int kbase = kt * 32 + (lane >> 4) * 8;
  unsigned short o[8];
#pragma unroll
  for (int j = 0; j < 8; ++j) o[j] = f2bf(W[(size_t)(kbase + j) * cols + n]);
  uint4 ov;
  ov.x = (uint32_t)o[0] | ((uint32_t)o[1] << 16);
  ov.y = (uint32_t)o[2] | ((uint32_t)o[3] << 16);
  ov.z = (uint32_t)o[4] | ((uint32_t)o[5] << 16);
  ov.w = (uint32_t)o[6] | ((uint32_t)o[7] << 16);
  *(uint4*)(wpack + obase + ((size_t)((ch * 16 + kt * 4 + nt) * 64 + lane)) * 8) = ov;
}

// ---------------- Gather-sum (bf16 in/out, fp32 accumulate) ----------------
// 16 threads/node, 16B loads; indices loaded coalesced 16-at-a-time, shfl-broadcast;
// 4-way unrolled inner loop with dual accumulators (4 loads in flight).
__global__ __launch_bounds__(256) void gather_kernel(
    const unsigned short* __restrict__ h, const int* __restrict__ csr,
    const int* __restrict__ off, unsigned short* __restrict__ out, int N) {
  const int tid = blockIdx.x * 256 + threadIdx.x;
  const int node = tid >> 4;
  if (node >= N) return;
  const int q = tid & 15;
  const int gb = (threadIdx.x & 63) & 48;  // group base within wave
  const uint4* hv = (const uint4*)h;
  const int beg = off[node];
  const int end = off[node + 1];

  const uint4 sv = hv[(size_t)node * 16 + q];
  float a0 = bf_lo(sv.x), a1 = bf_hi(sv.x), a2 = bf_lo(sv.y), a3 = bf_hi(sv.y);
  float a4 = bf_lo(sv.z), a5 = bf_hi(sv.z), a6 = bf_lo(sv.w), a7 = bf_hi(sv.w);
  float b0 = 0.f, b1 = 0.f, b2 = 0.f, b3 = 0.f, b4 = 0.f, b5 = 0.f, b6 = 0.f, b7 = 0.f;

  for (int e = beg; e < end; e += 16) {
    const int rem = end - e;
    const int cnt = rem < 16 ? rem : 16;
    const int idx = (q < cnt) ? csr[e + q] : 0;
    int j = 0;
    for (; j + 4 <= cnt; j += 4) {
      const int s0 = __shfl(idx, gb + j + 0, 64);
      const int s1 = __shfl(idx, gb + j + 1, 64);
      const int s2 = __shfl(idx, gb + j + 2, 64);
      const int s3 = __shfl(idx, gb + j + 3, 64);
      const uint4 v0 = hv[(size_t)s0 * 16 + q];
      const uint4 v1 = hv[(size_t)s1 * 16 + q];
      const uint4 v2 = hv[(size_t)s2 * 16 + q];
      const uint4 v3 = hv[(size_t)s3 * 16 + q];
      a0 += bf_lo(v0.x); a1 += bf_hi(v0.x); a2 += bf_lo(v0.y); a3 += bf_hi(v0.y);
      a4 += bf_lo(v0.z); a5 += bf_hi(v0.z); a6 += bf_lo(v0.w); a7 += bf_hi(v0.w);
      b0 += bf_lo(v1.x); b1 += bf_hi(v1.x); b2 += bf_lo(v1.y); b3 += bf_hi(v1.y);
      b4 += bf_lo(v1.z); b5 += bf_hi(v1.z); b6 += bf_lo(v1.w); b7 += bf_hi(v1.w);
      a0 += bf_lo(v2.x); a1 += bf_hi(v2.x); a2 += bf_lo(v2.y); a3 += bf_hi(v2.y);
      a4 += bf_lo(v2.z); a5 += bf_hi(v2.z); a6 += bf_lo(v2.w); a7 += bf_hi(v2.w);
      b0 += bf_lo(v3.x); b1 += bf_hi(v3.x); b2 += bf_lo(v3.y); b3 += bf_hi(v3.y);
      b4 += bf_lo(v3.z); b5 += bf_hi(v3.z); b6 += bf_lo(v3.w); b7 += bf_hi(v3.w);
    }
    for (; j < cnt; ++j) {
      const int s = __shfl(idx, gb + j, 64);
      const uint4 v = hv[(size_t)s * 16 + q];
      a0 += bf_lo(v.x); a1 += bf_hi(v.x); a2 += bf_lo(v.y); a3 += bf_hi(v.y);
      a4 += bf_lo(v.z); a5 += bf_hi(v.z); a6 += bf_lo(v.w); a7 += bf_hi(v.w);
    }
  }
  a0 += b0; a1 += b1; a2 += b2; a3 += b3;
  a4 += b4; a5 += b5; a6 += b6; a7 += b7;

  uint4 o;
  o.x = (uint32_t)f2bf(a0) | ((uint32_t)f2bf(a1) << 16);
  o.y = (uint32_t)f2bf(a2) | ((uint32_t)f2bf(a3) << 16);
  o.z = (uint32_t)f2bf(a4) | ((uint32_t)f2bf(a5) << 16);
  o.w = (uint32_t)f2bf(a6) | ((uint32_t)f2bf(a7) << 16);
  ((uint4*)out)[(size_t)node * 16 + q] = o;
}

// ---------------- MFMA GEMM: (M x 128 bf16) @ (128 x COLS) + bias [+relu][+drop] ----------------
template <int COLS, bool RELU, bool DROPOUT, bool OUT_BF16>
__global__ __launch_bounds__(256) void mfma_gemm(
    const unsigned short* __restrict__ A, const unsigned short* __restrict__ Wp,
    const float* __restrict__ bias, void* __restrict__ outv, int M,
    uint32_t k0, uint32_t k1) {
  constexpr int CH = COLS / 64;      // 2 or 1
  constexpr int BROWS = (4 / CH) * 16;
  const int wave = threadIdx.x >> 6;
  const int lane = threadIdx.x & 63;
  const int ch = wave % CH;
  const int rt = wave / CH;
  const int m = lane & 15;
  const int kg = lane >> 4;

  short8 bfrag[16];
  const short8* wp = (const short8*)Wp + (size_t)(ch * 16) * 64 + lane;
#pragma unroll
  for (int i = 0; i < 16; ++i) bfrag[i] = wp[(size_t)i * 64];

  const int row0 = blockIdx.x * BROWS + rt * 16;
  const int arow = (row0 + m < M) ? (row0 + m) : (M - 1);
  const short8* ap = (const short8*)(A + (size_t)arow * 128 + kg * 8);

  short8 afrag[4];
#pragma unroll
  for (int kt = 0; kt < 4; ++kt) afrag[kt] = ap[kt * 4];

  float4v acc[4] = {};
#pragma unroll
  for (int kt = 0; kt < 4; ++kt) {
#pragma unroll
    for (int nt = 0; nt < 4; ++nt)
      acc[nt] = __builtin_amdgcn_mfma_f32_16x16x32_bf16(
          afrag[kt], bfrag[kt * 4 + nt], acc[nt], 0, 0, 0);
  }

  const float KEEP_INV = 1.0f / 0.9f;
#pragma unroll
  for (int nt = 0; nt < 4; ++nt) {
    const int col = ch * 64 + nt * 16 + m;
    const float b = bias[col];
#pragma unroll
    for (int r = 0; r < 4; ++r) {
      const int ro = row0 + kg * 4 + r;
      if (ro >= M) continue;
      float v = acc[nt][r] + b;
      if (RELU) v = fmaxf(v, 0.0f);
      if (DROPOUT) {
        const uint32_t idx = (uint32_t)ro * 128u + (uint32_t)col;
        v = tf_keep(k0, k1, idx) ? v * KEEP_INV : 0.0f;
      }
      if (OUT_BF16)
        ((unsigned short*)outv)[(size_t)ro * COLS + col] = f2bf(v);
      else
        ((float*)outv)[(size_t)ro * COLS + col] = v;
    }
  }
}

// ---------------- Host launch ----------------
extern "C" void kernel_launch(void* const* d_in, const int* in_sizes, int n_in,
                              void* d_out, int out_size, void* d_ws, size_t ws_size,
                              hipStream_t stream) {
  const float* x    = (const float*)d_in[0];
  const int*   ei   = (const int*)d_in[1];
  const float* Ws1  = (const float*)d_in[2];
  const float* bs1  = (const float*)d_in[3];
  const float* Ws2  = (const float*)d_in[4];
  const float* bs2  = (const float*)d_in[5];
  const float* Wlin = (const float*)d_in[6];
  const float* blin = (const float*)d_in[7];

  const int N = in_sizes[0] / 128;
  const int E = in_sizes[1] / 2;
  const int* src = ei;
  const int* dst = ei + E;

  unsigned short* bufA = (unsigned short*)d_ws;           // h      (N*128 bf16)
  unsigned short* bufB = bufA + (size_t)N * 128;          // agg
  unsigned short* bufC = bufB + (size_t)N * 128;          // t1
  unsigned short* wpack = bufC + (size_t)N * 128;         // 106496 bf16
  int* counts  = (int*)(wpack + 106496 + 16);
  int* offsets = counts + N;
  int* cursor  = offsets + N + 1;
  int* csr     = cursor + N;
  int* bsum    = csr + E;

  uint32_t dk[3][2];
  for (int l = 0; l < 3; ++l)
    tf2x32(0u, 42u, 0u, (uint32_t)l, &dk[l][0], &dk[l][1]);

  const int eblocks = (E + 255) / 256;
  const int nb = (N + 255) / 256;   // 196 <= 256

  // CSR build
  hipMemsetAsync(counts, 0, (size_t)N * sizeof(int), stream);
  count_kernel<<<eblocks, 256, 0, stream>>>(dst, counts, E);
  scan1_kernel<<<nb, 256, 0, stream>>>(counts, bsum, N);
  scan2_kernel<<<1, 256, 0, stream>>>(bsum, nb);
  scan3_kernel<<<nb, 256, 0, stream>>>(counts, bsum, offsets, cursor, N);
  fill_kernel<<<eblocks, 256, 0, stream>>>(src, dst, cursor, csr, E);

  // Prep: x->bf16, weights->MFMA fragment layout
  convert_kernel<<<(N * 32 + 255) / 256, 256, 0, stream>>>(x, bufA, N * 32);
  repack_kernel<<<52, 256, 0, stream>>>(Ws1, Ws2, Wlin, wpack);

  const int g128 = (N + 31) / 32;
  const int g64  = (N + 63) / 64;
  const int gth  = (N * 16 + 255) / 256;

  for (int l = 0; l < 3; ++l) {
    gather_kernel<<<gth, 256, 0, stream>>>(bufA, csr, offsets, bufB, N);
    mfma_gemm<128, true, false, true><<<g128, 256, 0, stream>>>(
        bufB, wpack + (size_t)(l * 2) * 16384, bs1 + (size_t)l * 128, bufC, N, 0u, 0u);
    mfma_gemm<128, true, true, true><<<g128, 256, 0, stream>>>(
        bufC, wpack + (size_t)(l * 2 + 1) * 16384, bs2 + (size_t)l * 128, bufA, N,
        dk[l][0], dk[l][1]);
  }
  mfma_gemm<64, false, false, false><<<g64, 256, 0, stream>>>(
      bufA, wpack + 6 * 16384, blin, d_out, N, 0u, 0u);
}

// Round 5
// 380.638 us; speedup vs baseline: 11.6875x; 1.0115x over previous
//
#include <hip/hip_runtime.h>
#include <stdint.h>

typedef short short8 __attribute__((ext_vector_type(8)));   // 8 bf16 raw (4 VGPRs)
typedef float float4v __attribute__((ext_vector_type(4)));  // MFMA C/D frag

// ---------------- bf16 helpers (RNE) ----------------
__device__ static inline unsigned short f2bf(float f) {
  uint32_t u = __float_as_uint(f);
  u += 0x7fffu + ((u >> 16) & 1u);
  return (unsigned short)(u >> 16);
}
__device__ static inline float bf_lo(uint32_t v) { return __uint_as_float(v << 16); }
__device__ static inline float bf_hi(uint32_t v) { return __uint_as_float(v & 0xffff0000u); }

// ---------------- Threefry2x32 (exact JAX semantics, 20 rounds) ----------------
__host__ __device__ static inline void tf2x32(uint32_t k0, uint32_t k1,
                                              uint32_t x0, uint32_t x1,
                                              uint32_t* o0, uint32_t* o1) {
  const uint32_t ks2 = k0 ^ k1 ^ 0x1BD11BDAu;
  x0 += k0; x1 += k1;
#define TF_RND(r) { x0 += x1; x1 = (x1 << (r)) | (x1 >> (32 - (r))); x1 ^= x0; }
  TF_RND(13) TF_RND(15) TF_RND(26) TF_RND(6)
  x0 += k1;  x1 += ks2 + 1u;
  TF_RND(17) TF_RND(29) TF_RND(16) TF_RND(24)
  x0 += ks2; x1 += k0 + 2u;
  TF_RND(13) TF_RND(15) TF_RND(26) TF_RND(6)
  x0 += k0;  x1 += k1 + 3u;
  TF_RND(17) TF_RND(29) TF_RND(16) TF_RND(24)
  x0 += k1;  x1 += ks2 + 4u;
  TF_RND(13) TF_RND(15) TF_RND(26) TF_RND(6)
  x0 += ks2; x1 += k0 + 5u;
#undef TF_RND
  *o0 = x0; *o1 = x1;
}

__device__ static inline bool tf_keep(uint32_t k0, uint32_t k1, uint32_t idx) {
  uint32_t o0, o1;
  tf2x32(k0, k1, 0u, idx, &o0, &o1);
  const uint32_t bits = o0 ^ o1;
  const float u = __uint_as_float((bits >> 9) | 0x3f800000u) - 1.0f;
  return u < 0.9f;
}

// ---------------- Segmented CSR build (4 segments by blockIdx&3) ----------------
// count4 layout: [seg][node] flat (4N). csr layout: segment-major, node-minor.
__global__ __launch_bounds__(256) void count4_kernel(
    const int* __restrict__ dst, int* __restrict__ count4, int N, int E) {
  const int tid = blockIdx.x * 256 + threadIdx.x;
  const int nt4 = (E + 3) >> 2;
  if (tid >= nt4) return;
  int* cseg = count4 + (size_t)(blockIdx.x & 3) * N;
  const int base = tid * 4;
  if (base + 4 <= E) {
    const int4 d4 = ((const int4*)dst)[tid];
    atomicAdd(&cseg[d4.x], 1);
    atomicAdd(&cseg[d4.y], 1);
    atomicAdd(&cseg[d4.z], 1);
    atomicAdd(&cseg[d4.w], 1);
  } else {
    for (int k = base; k < E; ++k) atomicAdd(&cseg[dst[k]], 1);
  }
}

// Phase 1: per-block (256-elem) sums over flat count4[M4]
__global__ __launch_bounds__(256) void scan1_kernel(
    const int* __restrict__ count4, int* __restrict__ bsum, int M4) {
  __shared__ int red[4];
  const int i = blockIdx.x * 256 + threadIdx.x;
  int v = (i < M4) ? count4[i] : 0;
  for (int off = 32; off > 0; off >>= 1) v += __shfl_down(v, off, 64);
  if ((threadIdx.x & 63) == 0) red[threadIdx.x >> 6] = v;
  __syncthreads();
  if (threadIdx.x == 0) bsum[blockIdx.x] = red[0] + red[1] + red[2] + red[3];
}

// Phase 2: exclusive scan of nb block sums (any nb), single block, chunked.
__global__ __launch_bounds__(256) void scan2_kernel(int* __restrict__ bsum, int nb) {
  __shared__ int buf[256];
  __shared__ int carry_s;
  const int t = threadIdx.x;
  if (t == 0) carry_s = 0;
  __syncthreads();
  for (int base = 0; base < nb; base += 256) {
    const int c = carry_s;
    const int i = base + t;
    const int v = (i < nb) ? bsum[i] : 0;
    __syncthreads();
    buf[t] = v;
    __syncthreads();
    for (int off = 1; off < 256; off <<= 1) {
      const int add = (t >= off) ? buf[t - off] : 0;
      __syncthreads();
      buf[t] += add;
      __syncthreads();
    }
    if (i < nb) bsum[i] = c + ((t == 0) ? 0 : buf[t - 1]);
    if (t == 0) carry_s = c + buf[255];
    __syncthreads();
  }
}

// Phase 3: block-local scan + bsum -> cursor4[i] (sublist start) and transposed
// per-node table offsT8[node*8 + 2s]=start, [2s+1]=end for the gather.
__global__ __launch_bounds__(256) void scan3_kernel(
    const int* __restrict__ count4, const int* __restrict__ bsum,
    int* __restrict__ cursor4, int* __restrict__ offsT8, int N, int M4) {
  __shared__ int buf[256];
  const int t = threadIdx.x;
  const int i = blockIdx.x * 256 + t;
  const int c = (i < M4) ? count4[i] : 0;
  buf[t] = c;
  __syncthreads();
  for (int off = 1; off < 256; off <<= 1) {
    const int add = (t >= off) ? buf[t - off] : 0;
    __syncthreads();
    buf[t] += add;
    __syncthreads();
  }
  if (i < M4) {
    const int incl = bsum[blockIdx.x] + buf[t];
    const int start = incl - c;
    cursor4[i] = start;
    const int s = i / N;
    const int node = i - s * N;
    offsT8[(size_t)node * 8 + 2 * s] = start;
    offsT8[(size_t)node * 8 + 2 * s + 1] = incl;
  }
}

__global__ __launch_bounds__(256) void fill4_kernel(
    const int* __restrict__ src, const int* __restrict__ dst,
    int* __restrict__ cursor4, int* __restrict__ csr, int N, int E) {
  const int tid = blockIdx.x * 256 + threadIdx.x;
  const int nt4 = (E + 3) >> 2;
  if (tid >= nt4) return;
  int* cseg = cursor4 + (size_t)(blockIdx.x & 3) * N;
  const int base = tid * 4;
  if (base + 4 <= E) {
    const int4 s4 = ((const int4*)src)[tid];
    const int4 d4 = ((const int4*)dst)[tid];
    const int p0 = atomicAdd(&cseg[d4.x], 1);
    const int p1 = atomicAdd(&cseg[d4.y], 1);
    const int p2 = atomicAdd(&cseg[d4.z], 1);
    const int p3 = atomicAdd(&cseg[d4.w], 1);
    csr[p0] = s4.x; csr[p1] = s4.y; csr[p2] = s4.z; csr[p3] = s4.w;
  } else {
    for (int k = base; k < E; ++k) {
      const int pos = atomicAdd(&cseg[dst[k]], 1);
      csr[pos] = src[k];
    }
  }
}

// ---------------- x (fp32) -> bf16, fused with W repack ----------------
__global__ __launch_bounds__(256) void convrepack_kernel(
    const float* __restrict__ x, unsigned short* __restrict__ xb, int n4,
    const float* __restrict__ Ws1, const float* __restrict__ Ws2,
    const float* __restrict__ Wlin, unsigned short* __restrict__ wpack,
    int nconv_blocks) {
  if ((int)blockIdx.x < nconv_blocks) {
    const int i = blockIdx.x * 256 + threadIdx.x;
    if (i >= n4) return;
    const float4 v = ((const float4*)x)[i];
    uint2 o;
    o.x = (uint32_t)f2bf(v.x) | ((uint32_t)f2bf(v.y) << 16);
    o.y = (uint32_t)f2bf(v.z) | ((uint32_t)f2bf(v.w) << 16);
    ((uint2*)xb)[i] = o;
    return;
  }
  const int tid = (blockIdx.x - nconv_blocks) * 256 + threadIdx.x;  // 13312 total
  if (tid >= 13312) return;
  const float* W;
  int cols, r;
  size_t obase;
  if (tid < 12288) {
    const int m = tid / 2048;  // 0..5
    r = tid % 2048;
    const int l = m >> 1;
    W = (m & 1) ? (Ws2 + (size_t)l * 16384) : (Ws1 + (size_t)l * 16384);
    cols = 128;
    obase = (size_t)m * 16384;
  } else {
    r = tid - 12288;           // 0..1023
    W = Wlin;
    cols = 64;
    obase = 6 * 16384;
  }
  const int ch = (cols == 128) ? (r >> 10) : 0;
  const int kt = (r >> 8) & 3;
  const int nt = (r >> 6) & 3;
  const int lane = r & 63;
  const int n = ch * 64 + nt * 16 + (lane & 15);
  const int kbase = kt * 32 + (lane >> 4) * 8;
  unsigned short o[8];
#pragma unroll
  for (int j = 0; j < 8; ++j) o[j] = f2bf(W[(size_t)(kbase + j) * cols + n]);
  uint4 ov;
  ov.x = (uint32_t)o[0] | ((uint32_t)o[1] << 16);
  ov.y = (uint32_t)o[2] | ((uint32_t)o[3] << 16);
  ov.z = (uint32_t)o[4] | ((uint32_t)o[5] << 16);
  ov.w = (uint32_t)o[6] | ((uint32_t)o[7] << 16);
  *(uint4*)(wpack + obase + ((size_t)((ch * 16 + kt * 4 + nt) * 64 + lane)) * 8) = ov;
}

// ---------------- Gather-sum over 4 sublists (bf16 in/out, fp32 accumulate) ----------------
// 16 threads/node, 16B row loads; per-node offset table read as one coalesced
// 32B (8-lane) load; indices shfl-broadcast; 4-deep load pipelining, dual accs.
__global__ __launch_bounds__(256) void gather_kernel(
    const unsigned short* __restrict__ h, const int* __restrict__ csr,
    const int* __restrict__ offsT8, unsigned short* __restrict__ out, int N) {
  const int tid = blockIdx.x * 256 + threadIdx.x;
  const int node = tid >> 4;
  if (node >= N) return;
  const int q = tid & 15;
  const int gb = (threadIdx.x & 63) & 48;  // node's lane base within wave
  const uint4* hv = (const uint4*)h;

  const int o = (q < 8) ? offsT8[(size_t)node * 8 + q] : 0;

  const uint4 sv = hv[(size_t)node * 16 + q];
  float a0 = bf_lo(sv.x), a1 = bf_hi(sv.x), a2 = bf_lo(sv.y), a3 = bf_hi(sv.y);
  float a4 = bf_lo(sv.z), a5 = bf_hi(sv.z), a6 = bf_lo(sv.w), a7 = bf_hi(sv.w);
  float b0 = 0.f, b1 = 0.f, b2 = 0.f, b3 = 0.f, b4 = 0.f, b5 = 0.f, b6 = 0.f, b7 = 0.f;

#pragma unroll
  for (int s = 0; s < 4; ++s) {
    const int beg = __shfl(o, gb + 2 * s, 64);
    const int end = __shfl(o, gb + 2 * s + 1, 64);
    for (int e = beg; e < end; e += 16) {
      const int rem = end - e;
      const int cnt = rem < 16 ? rem : 16;
      const int idx = (q < cnt) ? csr[e + q] : 0;
      int j = 0;
      for (; j + 4 <= cnt; j += 4) {
        const int s0 = __shfl(idx, gb + j + 0, 64);
        const int s1 = __shfl(idx, gb + j + 1, 64);
        const int s2 = __shfl(idx, gb + j + 2, 64);
        const int s3 = __shfl(idx, gb + j + 3, 64);
        const uint4 v0 = hv[(size_t)s0 * 16 + q];
        const uint4 v1 = hv[(size_t)s1 * 16 + q];
        const uint4 v2 = hv[(size_t)s2 * 16 + q];
        const uint4 v3 = hv[(size_t)s3 * 16 + q];
        a0 += bf_lo(v0.x); a1 += bf_hi(v0.x); a2 += bf_lo(v0.y); a3 += bf_hi(v0.y);
        a4 += bf_lo(v0.z); a5 += bf_hi(v0.z); a6 += bf_lo(v0.w); a7 += bf_hi(v0.w);
        b0 += bf_lo(v1.x); b1 += bf_hi(v1.x); b2 += bf_lo(v1.y); b3 += bf_hi(v1.y);
        b4 += bf_lo(v1.z); b5 += bf_hi(v1.z); b6 += bf_lo(v1.w); b7 += bf_hi(v1.w);
        a0 += bf_lo(v2.x); a1 += bf_hi(v2.x); a2 += bf_lo(v2.y); a3 += bf_hi(v2.y);
        a4 += bf_lo(v2.z); a5 += bf_hi(v2.z); a6 += bf_lo(v2.w); a7 += bf_hi(v2.w);
        b0 += bf_lo(v3.x); b1 += bf_hi(v3.x); b2 += bf_lo(v3.y); b3 += bf_hi(v3.y);
        b4 += bf_lo(v3.z); b5 += bf_hi(v3.z); b6 += bf_lo(v3.w); b7 += bf_hi(v3.w);
      }
      for (; j < cnt; ++j) {
        const int sj = __shfl(idx, gb + j, 64);
        const uint4 v = hv[(size_t)sj * 16 + q];
        a0 += bf_lo(v.x); a1 += bf_hi(v.x); a2 += bf_lo(v.y); a3 += bf_hi(v.y);
        a4 += bf_lo(v.z); a5 += bf_hi(v.z); a6 += bf_lo(v.w); a7 += bf_hi(v.w);
      }
    }
  }
  a0 += b0; a1 += b1; a2 += b2; a3 += b3;
  a4 += b4; a5 += b5; a6 += b6; a7 += b7;

  uint4 ov;
  ov.x = (uint32_t)f2bf(a0) | ((uint32_t)f2bf(a1) << 16);
  ov.y = (uint32_t)f2bf(a2) | ((uint32_t)f2bf(a3) << 16);
  ov.z = (uint32_t)f2bf(a4) | ((uint32_t)f2bf(a5) << 16);
  ov.w = (uint32_t)f2bf(a6) | ((uint32_t)f2bf(a7) << 16);
  ((uint4*)out)[(size_t)node * 16 + q] = ov;
}

// ---------------- MFMA GEMM: (M x 128 bf16) @ (128 x COLS) + bias [+relu][+drop] ----------------
template <int COLS, bool RELU, bool DROPOUT, bool OUT_BF16>
__global__ __launch_bounds__(256) void mfma_gemm(
    const unsigned short* __restrict__ A, const unsigned short* __restrict__ Wp,
    const float* __restrict__ bias, void* __restrict__ outv, int M,
    uint32_t k0, uint32_t k1) {
  constexpr int CH = COLS / 64;      // 2 or 1
  constexpr int BROWS = (4 / CH) * 16;
  const int wave = threadIdx.x >> 6;
  const int lane = threadIdx.x & 63;
  const int ch = wave % CH;
  const int rt = wave / CH;
  const int m = lane & 15;
  const int kg = lane >> 4;

  short8 bfrag[16];
  const short8* wp = (const short8*)Wp + (size_t)(ch * 16) * 64 + lane;
#pragma unroll
  for (int i = 0; i < 16; ++i) bfrag[i] = wp[(size_t)i * 64];

  const int row0 = blockIdx.x * BROWS + rt * 16;
  const int arow = (row0 + m < M) ? (row0 + m) : (M - 1);
  const short8* ap = (const short8*)(A + (size_t)arow * 128 + kg * 8);

  short8 afrag[4];
#pragma unroll
  for (int kt = 0; kt < 4; ++kt) afrag[kt] = ap[kt * 4];

  float4v acc[4] = {};
#pragma unroll
  for (int kt = 0; kt < 4; ++kt) {
#pragma unroll
    for (int nt = 0; nt < 4; ++nt)
      acc[nt] = __builtin_amdgcn_mfma_f32_16x16x32_bf16(
          afrag[kt], bfrag[kt * 4 + nt], acc[nt], 0, 0, 0);
  }

  const float KEEP_INV = 1.0f / 0.9f;
#pragma unroll
  for (int nt = 0; nt < 4; ++nt) {
    const int col = ch * 64 + nt * 16 + m;
    const float b = bias[col];
#pragma unroll
    for (int r = 0; r < 4; ++r) {
      const int ro = row0 + kg * 4 + r;
      if (ro >= M) continue;
      float v = acc[nt][r] + b;
      if (RELU) v = fmaxf(v, 0.0f);
      if (DROPOUT) {
        const uint32_t idx = (uint32_t)ro * 128u + (uint32_t)col;
        v = tf_keep(k0, k1, idx) ? v * KEEP_INV : 0.0f;
      }
      if (OUT_BF16)
        ((unsigned short*)outv)[(size_t)ro * COLS + col] = f2bf(v);
      else
        ((float*)outv)[(size_t)ro * COLS + col] = v;
    }
  }
}

// ---------------- Host launch ----------------
extern "C" void kernel_launch(void* const* d_in, const int* in_sizes, int n_in,
                              void* d_out, int out_size, void* d_ws, size_t ws_size,
                              hipStream_t stream) {
  const float* x    = (const float*)d_in[0];
  const int*   ei   = (const int*)d_in[1];
  const float* Ws1  = (const float*)d_in[2];
  const float* bs1  = (const float*)d_in[3];
  const float* Ws2  = (const float*)d_in[4];
  const float* bs2  = (const float*)d_in[5];
  const float* Wlin = (const float*)d_in[6];
  const float* blin = (const float*)d_in[7];

  const int N = in_sizes[0] / 128;
  const int E = in_sizes[1] / 2;
  const int* src = ei;
  const int* dst = ei + E;
  const int M4 = 4 * N;

  unsigned short* bufA = (unsigned short*)d_ws;           // h      (N*128 bf16)
  unsigned short* bufB = bufA + (size_t)N * 128;          // agg
  unsigned short* bufC = bufB + (size_t)N * 128;          // t1
  unsigned short* wpack = bufC + (size_t)N * 128;         // 106496 bf16
  int* count4  = (int*)(wpack + 106496 + 16);             // 4N
  int* cursor4 = count4 + M4;                             // 4N
  int* offsT8  = cursor4 + M4;                            // 8N
  int* csr     = offsT8 + 8 * N;                          // E
  int* bsum    = csr + E;                                 // ceil(4N/256)

  uint32_t dk[3][2];
  for (int l = 0; l < 3; ++l)
    tf2x32(0u, 42u, 0u, (uint32_t)l, &dk[l][0], &dk[l][1]);

  const int nt4 = (E + 3) / 4;
  const int e4blocks = (nt4 + 255) / 256;
  const int nb4 = (M4 + 255) / 256;

  // Segmented CSR build
  hipMemsetAsync(count4, 0, (size_t)M4 * sizeof(int), stream);
  count4_kernel<<<e4blocks, 256, 0, stream>>>(dst, count4, N, E);
  scan1_kernel<<<nb4, 256, 0, stream>>>(count4, bsum, M4);
  scan2_kernel<<<1, 256, 0, stream>>>(bsum, nb4);
  scan3_kernel<<<nb4, 256, 0, stream>>>(count4, bsum, cursor4, offsT8, N, M4);
  fill4_kernel<<<e4blocks, 256, 0, stream>>>(src, dst, cursor4, csr, N, E);

  // Prep: x->bf16 + weights->MFMA fragment layout (fused)
  const int nconv = (N * 32 + 255) / 256;
  convrepack_kernel<<<nconv + 52, 256, 0, stream>>>(
      x, bufA, N * 32, Ws1, Ws2, Wlin, wpack, nconv);

  const int g128 = (N + 31) / 32;
  const int g64  = (N + 63) / 64;
  const int gth  = (N * 16 + 255) / 256;

  for (int l = 0; l < 3; ++l) {
    gather_kernel<<<gth, 256, 0, stream>>>(bufA, csr, offsT8, bufB, N);
    mfma_gemm<128, true, false, true><<<g128, 256, 0, stream>>>(
        bufB, wpack + (size_t)(l * 2) * 16384, bs1 + (size_t)l * 128, bufC, N, 0u, 0u);
    mfma_gemm<128, true, true, true><<<g128, 256, 0, stream>>>(
        bufC, wpack + (size_t)(l * 2 + 1) * 16384, bs2 + (size_t)l * 128, bufA, N,
        dk[l][0], dk[l][1]);
  }
  mfma_gemm<64, false, false, false><<<g64, 256, 0, stream>>>(
      bufA, wpack + 6 * 16384, blin, d_out, N, 0u, 0u);
}

// Round 6
// 339.780 us; speedup vs baseline: 13.0929x; 1.1202x over previous
//
#include <hip/hip_runtime.h>
#include <stdint.h>

typedef short short8 __attribute__((ext_vector_type(8)));   // 8 bf16 raw (4 VGPRs)
typedef float float4v __attribute__((ext_vector_type(4)));  // MFMA C/D frag

// ---------------- bf16 helpers (RNE) ----------------
__device__ static inline unsigned short f2bf(float f) {
  uint32_t u = __float_as_uint(f);
  u += 0x7fffu + ((u >> 16) & 1u);
  return (unsigned short)(u >> 16);
}
__device__ static inline float bf_lo(uint32_t v) { return __uint_as_float(v << 16); }
__device__ static inline float bf_hi(uint32_t v) { return __uint_as_float(v & 0xffff0000u); }

// ---------------- Threefry2x32 (exact JAX semantics, 20 rounds) ----------------
__host__ __device__ static inline void tf2x32(uint32_t k0, uint32_t k1,
                                              uint32_t x0, uint32_t x1,
                                              uint32_t* o0, uint32_t* o1) {
  const uint32_t ks2 = k0 ^ k1 ^ 0x1BD11BDAu;
  x0 += k0; x1 += k1;
#define TF_RND(r) { x0 += x1; x1 = (x1 << (r)) | (x1 >> (32 - (r))); x1 ^= x0; }
  TF_RND(13) TF_RND(15) TF_RND(26) TF_RND(6)
  x0 += k1;  x1 += ks2 + 1u;
  TF_RND(17) TF_RND(29) TF_RND(16) TF_RND(24)
  x0 += ks2; x1 += k0 + 2u;
  TF_RND(13) TF_RND(15) TF_RND(26) TF_RND(6)
  x0 += k0;  x1 += k1 + 3u;
  TF_RND(17) TF_RND(29) TF_RND(16) TF_RND(24)
  x0 += k1;  x1 += ks2 + 4u;
  TF_RND(13) TF_RND(15) TF_RND(26) TF_RND(6)
  x0 += ks2; x1 += k0 + 5u;
#undef TF_RND
  *o0 = x0; *o1 = x1;
}

__device__ static inline bool tf_keep(uint32_t k0, uint32_t k1, uint32_t idx) {
  uint32_t o0, o1;
  tf2x32(k0, k1, 0u, idx, &o0, &o1);
  const uint32_t bits = o0 ^ o1;
  const float u = __uint_as_float((bits >> 9) | 0x3f800000u) - 1.0f;
  return u < 0.9f;
}

// ---------------- Fused prep: count8 (blocks < nCnt) + x->bf16 + W repack ----------------
__global__ __launch_bounds__(256) void prep_kernel(
    const int* __restrict__ dst, int* __restrict__ count8, int N, int E,
    const float* __restrict__ x, unsigned short* __restrict__ xb, int n4,
    const float* __restrict__ Ws1, const float* __restrict__ Ws2,
    const float* __restrict__ Wlin, unsigned short* __restrict__ wpack,
    int nCnt, int nConv) {
  const int t = threadIdx.x;
  if ((int)blockIdx.x < nCnt) {
    const int tid = blockIdx.x * 256 + t;
    const int nt4 = (E + 3) >> 2;
    if (tid >= nt4) return;
    int* cseg = count8 + (size_t)(blockIdx.x & 7) * N;   // seg = XCD id
    const int base = tid * 4;
    if (base + 4 <= E) {
      const int4 d4 = ((const int4*)dst)[tid];
      atomicAdd(&cseg[d4.x], 1);
      atomicAdd(&cseg[d4.y], 1);
      atomicAdd(&cseg[d4.z], 1);
      atomicAdd(&cseg[d4.w], 1);
    } else {
      for (int k = base; k < E; ++k) atomicAdd(&cseg[dst[k]], 1);
    }
    return;
  }
  const int cb = blockIdx.x - nCnt;
  if (cb < nConv) {
    const int i = cb * 256 + t;
    if (i >= n4) return;
    const float4 v = ((const float4*)x)[i];
    uint2 o;
    o.x = (uint32_t)f2bf(v.x) | ((uint32_t)f2bf(v.y) << 16);
    o.y = (uint32_t)f2bf(v.z) | ((uint32_t)f2bf(v.w) << 16);
    ((uint2*)xb)[i] = o;
    return;
  }
  const int tid = (cb - nConv) * 256 + t;  // 13312 total repack threads
  if (tid >= 13312) return;
  const float* W;
  int cols, r;
  size_t obase;
  if (tid < 12288) {
    const int m = tid / 2048;  // 0..5
    r = tid % 2048;
    const int l = m >> 1;
    W = (m & 1) ? (Ws2 + (size_t)l * 16384) : (Ws1 + (size_t)l * 16384);
    cols = 128;
    obase = (size_t)m * 16384;
  } else {
    r = tid - 12288;           // 0..1023
    W = Wlin;
    cols = 64;
    obase = 6 * 16384;
  }
  const int ch = (cols == 128) ? (r >> 10) : 0;
  const int kt = (r >> 8) & 3;
  const int nt = (r >> 6) & 3;
  const int lane = r & 63;
  const int n = ch * 64 + nt * 16 + (lane & 15);
  const int kbase = kt * 32 + (lane >> 4) * 8;
  unsigned short o[8];
#pragma unroll
  for (int j = 0; j < 8; ++j) o[j] = f2bf(W[(size_t)(kbase + j) * cols + n]);
  uint4 ov;
  ov.x = (uint32_t)o[0] | ((uint32_t)o[1] << 16);
  ov.y = (uint32_t)o[2] | ((uint32_t)o[3] << 16);
  ov.z = (uint32_t)o[4] | ((uint32_t)o[5] << 16);
  ov.w = (uint32_t)o[6] | ((uint32_t)o[7] << 16);
  *(uint4*)(wpack + obase + ((size_t)((ch * 16 + kt * 4 + nt) * 64 + lane)) * 8) = ov;
}

// ---------------- Scan (3 phases) over flat count8[M8] ----------------
__global__ __launch_bounds__(256) void scan1_kernel(
    const int* __restrict__ count8, int* __restrict__ bsum, int M8) {
  __shared__ int red[4];
  const int i = blockIdx.x * 256 + threadIdx.x;
  int v = (i < M8) ? count8[i] : 0;
  for (int off = 32; off > 0; off >>= 1) v += __shfl_down(v, off, 64);
  if ((threadIdx.x & 63) == 0) red[threadIdx.x >> 6] = v;
  __syncthreads();
  if (threadIdx.x == 0) bsum[blockIdx.x] = red[0] + red[1] + red[2] + red[3];
}

__global__ __launch_bounds__(256) void scan2_kernel(int* __restrict__ bsum, int nb) {
  __shared__ int buf[256];
  __shared__ int carry_s;
  const int t = threadIdx.x;
  if (t == 0) carry_s = 0;
  __syncthreads();
  for (int base = 0; base < nb; base += 256) {
    const int c = carry_s;
    const int i = base + t;
    const int v = (i < nb) ? bsum[i] : 0;
    __syncthreads();
    buf[t] = v;
    __syncthreads();
    for (int off = 1; off < 256; off <<= 1) {
      const int add = (t >= off) ? buf[t - off] : 0;
      __syncthreads();
      buf[t] += add;
      __syncthreads();
    }
    if (i < nb) bsum[i] = c + ((t == 0) ? 0 : buf[t - 1]);
    if (t == 0) carry_s = c + buf[255];
    __syncthreads();
  }
}

// cursor8[i] = exclusive-prefix (sublist start). After fill8, cursor8[i] == end.
__global__ __launch_bounds__(256) void scan3_kernel(
    const int* __restrict__ count8, const int* __restrict__ bsum,
    int* __restrict__ cursor8, int M8) {
  __shared__ int buf[256];
  const int t = threadIdx.x;
  const int i = blockIdx.x * 256 + t;
  const int c = (i < M8) ? count8[i] : 0;
  buf[t] = c;
  __syncthreads();
  for (int off = 1; off < 256; off <<= 1) {
    const int add = (t >= off) ? buf[t - off] : 0;
    __syncthreads();
    buf[t] += add;
    __syncthreads();
  }
  if (i < M8) cursor8[i] = bsum[blockIdx.x] + buf[t] - c;
}

__global__ __launch_bounds__(256) void fill8_kernel(
    const int* __restrict__ src, const int* __restrict__ dst,
    int* __restrict__ cursor8, int* __restrict__ csr, int N, int E) {
  const int tid = blockIdx.x * 256 + threadIdx.x;
  const int nt4 = (E + 3) >> 2;
  if (tid >= nt4) return;
  int* cseg = cursor8 + (size_t)(blockIdx.x & 7) * N;
  const int base = tid * 4;
  if (base + 4 <= E) {
    const int4 s4 = ((const int4*)src)[tid];
    const int4 d4 = ((const int4*)dst)[tid];
    const int p0 = atomicAdd(&cseg[d4.x], 1);
    const int p1 = atomicAdd(&cseg[d4.y], 1);
    const int p2 = atomicAdd(&cseg[d4.z], 1);
    const int p3 = atomicAdd(&cseg[d4.w], 1);
    csr[p0] = s4.x; csr[p1] = s4.y; csr[p2] = s4.z; csr[p3] = s4.w;
  } else {
    for (int k = base; k < E; ++k) {
      const int pos = atomicAdd(&cseg[dst[k]], 1);
      csr[pos] = src[k];
    }
  }
}

// ---------------- Fused GIN layer: gather -> MLP1 -> MLP2(+dropout) ----------------
// Block = 256 threads (4 waves) = 64 nodes. agg/t1 staged in LDS (stride 136 bf16).
__global__ __launch_bounds__(256) void gin_layer_kernel(
    const unsigned short* __restrict__ hIn, unsigned short* __restrict__ hOut,
    const int* __restrict__ csr, const int* __restrict__ cursor8,
    const int* __restrict__ count8,
    const unsigned short* __restrict__ W1p, const float* __restrict__ b1,
    const unsigned short* __restrict__ W2p, const float* __restrict__ b2,
    int N, uint32_t k0, uint32_t k1) {
  __shared__ __align__(16) unsigned short agg[64 * 136];
  __shared__ __align__(16) unsigned short t1[64 * 136];
  const int t = threadIdx.x;
  const int q = t & 15;
  const int gb = (t & 63) & 48;  // 16-lane group base within wave
  const int node0 = blockIdx.x * 64;
  const uint4* hv = (const uint4*)hIn;

  // ---- stage 0: gather 64 nodes into LDS agg (16 threads/node, 4 passes) ----
  for (int p = 0; p < 4; ++p) {
    const int nn = p * 16 + (t >> 4);
    const int node = node0 + nn;
    if (node < N) {
      int oe = 0, ol = 0;
      if (q < 8) {
        oe = cursor8[(size_t)q * N + node];   // end of sublist q (post-fill)
        ol = count8[(size_t)q * N + node];    // length
      }
      int b0, b1s, b2s, b3s, b4s, b5s, b6s, b7s;
      int l0, l1, l2, l3, l4, l5, l6, l7;
      {
        int e;
        e = __shfl(oe, gb + 0, 64); l0 = __shfl(ol, gb + 0, 64); b0  = e - l0;
        e = __shfl(oe, gb + 1, 64); l1 = __shfl(ol, gb + 1, 64); b1s = e - l1;
        e = __shfl(oe, gb + 2, 64); l2 = __shfl(ol, gb + 2, 64); b2s = e - l2;
        e = __shfl(oe, gb + 3, 64); l3 = __shfl(ol, gb + 3, 64); b3s = e - l3;
        e = __shfl(oe, gb + 4, 64); l4 = __shfl(ol, gb + 4, 64); b4s = e - l4;
        e = __shfl(oe, gb + 5, 64); l5 = __shfl(ol, gb + 5, 64); b5s = e - l5;
        e = __shfl(oe, gb + 6, 64); l6 = __shfl(ol, gb + 6, 64); b6s = e - l6;
        e = __shfl(oe, gb + 7, 64); l7 = __shfl(ol, gb + 7, 64); b7s = e - l7;
      }
      const int c1 = l0, c2 = c1 + l1, c3 = c2 + l2, c4 = c3 + l3;
      const int c5 = c4 + l4, c6 = c5 + l5, c7 = c6 + l6, T = c7 + l7;

      const uint4 sv = hv[(size_t)node * 16 + q];  // self term (eps=0)
      float a0 = bf_lo(sv.x), a1 = bf_hi(sv.x), a2 = bf_lo(sv.y), a3 = bf_hi(sv.y);
      float a4 = bf_lo(sv.z), a5 = bf_hi(sv.z), a6 = bf_lo(sv.w), a7 = bf_hi(sv.w);
      float d0 = 0.f, d1 = 0.f, d2 = 0.f, d3 = 0.f, d4 = 0.f, d5 = 0.f, d6 = 0.f, d7 = 0.f;

      for (int base = 0; base < T; base += 16) {
        const int rem = T - base;
        const int cnt = rem < 16 ? rem : 16;
        const int j = base + q;
        int pos = b0 + j;
        pos = (j >= c1) ? (b1s + j - c1) : pos;
        pos = (j >= c2) ? (b2s + j - c2) : pos;
        pos = (j >= c3) ? (b3s + j - c3) : pos;
        pos = (j >= c4) ? (b4s + j - c4) : pos;
        pos = (j >= c5) ? (b5s + j - c5) : pos;
        pos = (j >= c6) ? (b6s + j - c6) : pos;
        pos = (j >= c7) ? (b7s + j - c7) : pos;
        const int idx = (q < cnt) ? csr[pos] : 0;
        int jj = 0;
        for (; jj + 4 <= cnt; jj += 4) {
          const int s0 = __shfl(idx, gb + jj + 0, 64);
          const int s1 = __shfl(idx, gb + jj + 1, 64);
          const int s2 = __shfl(idx, gb + jj + 2, 64);
          const int s3 = __shfl(idx, gb + jj + 3, 64);
          const uint4 v0 = hv[(size_t)s0 * 16 + q];
          const uint4 v1 = hv[(size_t)s1 * 16 + q];
          const uint4 v2 = hv[(size_t)s2 * 16 + q];
          const uint4 v3 = hv[(size_t)s3 * 16 + q];
          a0 += bf_lo(v0.x); a1 += bf_hi(v0.x); a2 += bf_lo(v0.y); a3 += bf_hi(v0.y);
          a4 += bf_lo(v0.z); a5 += bf_hi(v0.z); a6 += bf_lo(v0.w); a7 += bf_hi(v0.w);
          d0 += bf_lo(v1.x); d1 += bf_hi(v1.x); d2 += bf_lo(v1.y); d3 += bf_hi(v1.y);
          d4 += bf_lo(v1.z); d5 += bf_hi(v1.z); d6 += bf_lo(v1.w); d7 += bf_hi(v1.w);
          a0 += bf_lo(v2.x); a1 += bf_hi(v2.x); a2 += bf_lo(v2.y); a3 += bf_hi(v2.y);
          a4 += bf_lo(v2.z); a5 += bf_hi(v2.z); a6 += bf_lo(v2.w); a7 += bf_hi(v2.w);
          d0 += bf_lo(v3.x); d1 += bf_hi(v3.x); d2 += bf_lo(v3.y); d3 += bf_hi(v3.y);
          d4 += bf_lo(v3.z); d5 += bf_hi(v3.z); d6 += bf_lo(v3.w); d7 += bf_hi(v3.w);
        }
        for (; jj < cnt; ++jj) {
          const int sj = __shfl(idx, gb + jj, 64);
          const uint4 v = hv[(size_t)sj * 16 + q];
          a0 += bf_lo(v.x); a1 += bf_hi(v.x); a2 += bf_lo(v.y); a3 += bf_hi(v.y);
          a4 += bf_lo(v.z); a5 += bf_hi(v.z); a6 += bf_lo(v.w); a7 += bf_hi(v.w);
        }
      }
      a0 += d0; a1 += d1; a2 += d2; a3 += d3;
      a4 += d4; a5 += d5; a6 += d6; a7 += d7;

      uint4 ov;
      ov.x = (uint32_t)f2bf(a0) | ((uint32_t)f2bf(a1) << 16);
      ov.y = (uint32_t)f2bf(a2) | ((uint32_t)f2bf(a3) << 16);
      ov.z = (uint32_t)f2bf(a4) | ((uint32_t)f2bf(a5) << 16);
      ov.w = (uint32_t)f2bf(a6) | ((uint32_t)f2bf(a7) << 16);
      *(uint4*)(agg + (size_t)nn * 136 + q * 8) = ov;
    }
  }
  __syncthreads();

  // ---- stage 1: t1 = relu(agg @ W1 + b1) ----
  const int wave = t >> 6, lane = t & 63;
  const int ch = wave & 1;        // col half
  const int rtw = wave >> 1;      // row-tile pair (2 tiles each)
  const int m = lane & 15, kg = lane >> 4;

  short8 bfrag[16];
  {
    const short8* wp = (const short8*)W1p + (size_t)(ch * 16) * 64 + lane;
#pragma unroll
    for (int i = 0; i < 16; ++i) bfrag[i] = wp[(size_t)i * 64];
  }
  float4v acc[2][4] = {};
#pragma unroll
  for (int rt = 0; rt < 2; ++rt) {
    const int lrow = (rtw * 2 + rt) * 16 + m;
#pragma unroll
    for (int kt = 0; kt < 4; ++kt) {
      const short8 af = *(const short8*)(agg + (size_t)lrow * 136 + kt * 32 + kg * 8);
#pragma unroll
      for (int nt = 0; nt < 4; ++nt)
        acc[rt][nt] = __builtin_amdgcn_mfma_f32_16x16x32_bf16(
            af, bfrag[kt * 4 + nt], acc[rt][nt], 0, 0, 0);
    }
  }
#pragma unroll
  for (int rt = 0; rt < 2; ++rt) {
#pragma unroll
    for (int nt = 0; nt < 4; ++nt) {
      const int col = ch * 64 + nt * 16 + m;
      const float bb = b1[col];
#pragma unroll
      for (int r = 0; r < 4; ++r) {
        const int lrow = (rtw * 2 + rt) * 16 + kg * 4 + r;
        float v = acc[rt][nt][r] + bb;
        v = fmaxf(v, 0.0f);
        t1[(size_t)lrow * 136 + col] = f2bf(v);
      }
    }
  }
  __syncthreads();

  // ---- stage 2: h' = dropout(relu(t1 @ W2 + b2)) ----
  {
    const short8* wp = (const short8*)W2p + (size_t)(ch * 16) * 64 + lane;
#pragma unroll
    for (int i = 0; i < 16; ++i) bfrag[i] = wp[(size_t)i * 64];
  }
  float4v acc2[2][4] = {};
#pragma unroll
  for (int rt = 0; rt < 2; ++rt) {
    const int lrow = (rtw * 2 + rt) * 16 + m;
#pragma unroll
    for (int kt = 0; kt < 4; ++kt) {
      const short8 af = *(const short8*)(t1 + (size_t)lrow * 136 + kt * 32 + kg * 8);
#pragma unroll
      for (int nt = 0; nt < 4; ++nt)
        acc2[rt][nt] = __builtin_amdgcn_mfma_f32_16x16x32_bf16(
            af, bfrag[kt * 4 + nt], acc2[rt][nt], 0, 0, 0);
    }
  }
  const float KEEP_INV = 1.0f / 0.9f;
#pragma unroll
  for (int rt = 0; rt < 2; ++rt) {
#pragma unroll
    for (int nt = 0; nt < 4; ++nt) {
      const int col = ch * 64 + nt * 16 + m;
      const float bb = b2[col];
#pragma unroll
      for (int r = 0; r < 4; ++r) {
        const int ro = node0 + (rtw * 2 + rt) * 16 + kg * 4 + r;
        if (ro >= N) continue;
        float v = acc2[rt][nt][r] + bb;
        v = fmaxf(v, 0.0f);
        const uint32_t idx = (uint32_t)ro * 128u + (uint32_t)col;
        v = tf_keep(k0, k1, idx) ? v * KEEP_INV : 0.0f;
        hOut[(size_t)ro * 128 + col] = f2bf(v);
      }
    }
  }
}

// ---------------- Final MFMA GEMM: (M x 128) @ (128 x 64) + bias, fp32 out ----------------
__global__ __launch_bounds__(256) void final_gemm_kernel(
    const unsigned short* __restrict__ A, const unsigned short* __restrict__ Wp,
    const float* __restrict__ bias, float* __restrict__ out, int M) {
  const int wave = threadIdx.x >> 6;
  const int lane = threadIdx.x & 63;
  const int m = lane & 15;
  const int kg = lane >> 4;

  short8 bfrag[16];
  const short8* wp = (const short8*)Wp + lane;
#pragma unroll
  for (int i = 0; i < 16; ++i) bfrag[i] = wp[(size_t)i * 64];

  const int row0 = blockIdx.x * 64 + wave * 16;
  const int arow = (row0 + m < M) ? (row0 + m) : (M - 1);
  const short8* ap = (const short8*)(A + (size_t)arow * 128 + kg * 8);

  short8 afrag[4];
#pragma unroll
  for (int kt = 0; kt < 4; ++kt) afrag[kt] = ap[kt * 4];

  float4v acc[4] = {};
#pragma unroll
  for (int kt = 0; kt < 4; ++kt) {
#pragma unroll
    for (int nt = 0; nt < 4; ++nt)
      acc[nt] = __builtin_amdgcn_mfma_f32_16x16x32_bf16(
          afrag[kt], bfrag[kt * 4 + nt], acc[nt], 0, 0, 0);
  }

#pragma unroll
  for (int nt = 0; nt < 4; ++nt) {
    const int col = nt * 16 + m;
    const float b = bias[col];
#pragma unroll
    for (int r = 0; r < 4; ++r) {
      const int ro = row0 + kg * 4 + r;
      if (ro >= M) continue;
      out[(size_t)ro * 64 + col] = acc[nt][r] + b;
    }
  }
}

// ---------------- Host launch ----------------
extern "C" void kernel_launch(void* const* d_in, const int* in_sizes, int n_in,
                              void* d_out, int out_size, void* d_ws, size_t ws_size,
                              hipStream_t stream) {
  const float* x    = (const float*)d_in[0];
  const int*   ei   = (const int*)d_in[1];
  const float* Ws1  = (const float*)d_in[2];
  const float* bs1  = (const float*)d_in[3];
  const float* Ws2  = (const float*)d_in[4];
  const float* bs2  = (const float*)d_in[5];
  const float* Wlin = (const float*)d_in[6];
  const float* blin = (const float*)d_in[7];

  const int N = in_sizes[0] / 128;
  const int E = in_sizes[1] / 2;
  const int* src = ei;
  const int* dst = ei + E;
  const int M8 = 8 * N;

  unsigned short* bufA  = (unsigned short*)d_ws;          // h ping (N*128 bf16)
  unsigned short* bufB  = bufA + (size_t)N * 128;         // h pong
  unsigned short* wpack = bufB + (size_t)N * 128;         // 106496 bf16 (+pad)
  int* count8  = (int*)(wpack + 106512);                  // 8N
  int* cursor8 = count8 + M8;                             // 8N
  int* csr     = cursor8 + M8;                            // E
  int* bsum    = csr + E;                                 // ceil(8N/256)

  uint32_t dk[3][2];
  for (int l = 0; l < 3; ++l)
    tf2x32(0u, 42u, 0u, (uint32_t)l, &dk[l][0], &dk[l][1]);

  const int nt4 = (E + 3) / 4;
  const int eblocks = (nt4 + 255) / 256;        // 782 -> seg = blockIdx&7
  const int nb8 = (M8 + 255) / 256;             // 1563
  const int nconv = (N * 32 + 255) / 256;       // x->bf16 blocks
  const int lblocks = (N + 63) / 64;            // 782

  // CSR build + prep
  hipMemsetAsync(count8, 0, (size_t)M8 * sizeof(int), stream);
  prep_kernel<<<eblocks + nconv + 52, 256, 0, stream>>>(
      dst, count8, N, E, x, bufA, N * 32, Ws1, Ws2, Wlin, wpack, eblocks, nconv);
  scan1_kernel<<<nb8, 256, 0, stream>>>(count8, bsum, M8);
  scan2_kernel<<<1, 256, 0, stream>>>(bsum, nb8);
  scan3_kernel<<<nb8, 256, 0, stream>>>(count8, bsum, cursor8, M8);
  fill8_kernel<<<eblocks, 256, 0, stream>>>(src, dst, cursor8, csr, N, E);
  // after fill8: cursor8[i] == end of sublist i, count8[i] == length

  // 3 fused GIN layers (ping-pong bufA <-> bufB)
  unsigned short* hin = bufA;
  unsigned short* hout = bufB;
  for (int l = 0; l < 3; ++l) {
    gin_layer_kernel<<<lblocks, 256, 0, stream>>>(
        hin, hout, csr, cursor8, count8,
        wpack + (size_t)(l * 2) * 16384, bs1 + (size_t)l * 128,
        wpack + (size_t)(l * 2 + 1) * 16384, bs2 + (size_t)l * 128,
        N, dk[l][0], dk[l][1]);
    unsigned short* tmp = hin; hin = hout; hout = tmp;
  }

  // out = h @ Wlin + blin  (h is in `hin` after final swap)
  final_gemm_kernel<<<lblocks, 256, 0, stream>>>(
      hin, wpack + 6 * 16384, blin, (float*)d_out, N);
}